// Round 17
// baseline (181.780 us; speedup 1.0000x reference)
//
#include <hip/hip_runtime.h>
#include <hip/hip_bf16.h>
#include <math.h>

#define DD 768
#define BB 32
#define PP 512
#define TT 512
#define CC 97
#define THRESH 0.8f
#define BK 32

typedef __attribute__((ext_vector_type(8))) short short8;
typedef __attribute__((ext_vector_type(4))) float f32x4;
typedef float4 f4u __attribute__((aligned(4)));

__device__ __forceinline__ short bfc(float x) {
    __hip_bfloat16 h = __float2bfloat16(x);
    return *(short*)&h;
}

// ---------------- fused match: raw fp32 -> bf16 staged dual-GEMM -------------
// R17 = R10 (best: 73.4us; 256p x 128t, 8 waves, wave = 64p x 128t, bf16 LDS
// 2 x 48KB, single barrier/step, fused cosine: raw dots + sq-from-staging-regs,
// rsqrt at epilogue) + R15's PROVEN depth-3 E/O register staging applied to
// this geometry: iter t: COMPUTE(buf t%2) -> WRSET(set (t+1)%2 -> other buf)
// -> LDSET(same set <- tile t+3) -> barrier. Loads rest TWO full steps
// (~5000cyc >> HBM 900cyc) before their ds_write -> no exposed vmcnt stall
// (R10's loads rested only ~600cyc). Regs ~220 unified <= 240 -> still
// 2 waves/SIMD, no spill (R15 verified the E/O pattern is scratch-free).
__global__ __launch_bounds__(512, 2) void match_kernel(
        const float* __restrict__ pairs, const float* __restrict__ trip,
        float* __restrict__ cand_v, int* __restrict__ cand_t) {
    __shared__ __align__(16) char smem[98304];    // 2 x 48KB (Ah16|At16|Bh8|Bt8)
    __shared__ float norms[768];                  // [Ah256|At256|Bh128|Bt128]

    // XCD swizzle (256 blocks, %8==0 -> bijective)
    int bid = blockIdx.x;
    int swz = (bid & 7) * 32 + (bid >> 3);
    int b = swz >> 3, sub = swz & 7;
    int pblk = sub >> 2, tblk = sub & 3;          // 2 p-blocks x 4 t-blocks

    int tid = threadIdx.x;
    int w = tid >> 6, l = tid & 63;
    int l15 = l & 15, lg = l >> 4;
    int ln = tid & 3;

    const float* pairs_b = pairs + ((size_t)b * PP + pblk * 256) * (2 * DD);
    const float* trip_b  = trip  + ((size_t)b * TT + tblk * 128) * (2 * DD + 1);

    // staging: 6 pieces/thread; seg s = tid + 512r (768 row-segs of 64B bf16),
    // lane ln = s&3; source chunk = ln ^ ((row>>1)&3) (verified bf16 swizzle).
    // segs: [Ah rows 0-255 | At rows 0-255 | Bh rows 0-127 | Bt rows 0-127].
    // rows: piece0/1 -> Ah row tid>>2 / 128+(tid>>2); piece2/3 -> At same;
    // piece4 -> Bh row tid>>2 (tid<512 covers 0-127); piece5 -> Bt.
    int srow = tid >> 2;
    int xch_c = ln ^ ((srow >> 1) & 3);           // same for srow and srow+128
    const float* spA0 = pairs_b + (size_t)srow * 1536 + xch_c * 8;          // Ah lo
    const float* spA1 = pairs_b + (size_t)(srow + 128) * 1536 + xch_c * 8;  // Ah hi
    const float* spB  = trip_b + (size_t)srow * 1537 + xch_c * 8;           // Bh
    // At = spA0/spA1 + 768 ; Bt = spB + 769
    int dst = tid * 16;   // piece dests: 0,4096(Ah hi),8192,12288(At),16384,20480

    // two full staging sets (12 float4 each): E = even tiles, O = odd tiles
    float4 E0, E1, E2, E3, E4, E5, E6, E7, E8, E9, E10, E11;
    float4 O0, O1, O2, O3, O4, O5, O6, O7, O8, O9, O10, O11;
    float sq0 = 0.f, sq1 = 0.f, sq2 = 0.f, sq3 = 0.f, sq4 = 0.f, sq5 = 0.f;

#define LDSET(P, ko)                                                          \
    do {                                                                      \
        P##0  = *(const f4u*)(spA0 + (ko));        P##1  = *(const f4u*)(spA0 + (ko) + 4); \
        P##2  = *(const f4u*)(spA1 + (ko));        P##3  = *(const f4u*)(spA1 + (ko) + 4); \
        P##4  = *(const f4u*)(spA0 + (ko) + 768);  P##5  = *(const f4u*)(spA0 + (ko) + 772); \
        P##6  = *(const f4u*)(spA1 + (ko) + 768);  P##7  = *(const f4u*)(spA1 + (ko) + 772); \
        P##8  = *(const f4u*)(spB + (ko));         P##9  = *(const f4u*)(spB + (ko) + 4); \
        P##10 = *(const f4u*)(spB + (ko) + 769);   P##11 = *(const f4u*)(spB + (ko) + 773); \
    } while (0)
#define WRQ(sqv, nb, off, A, Bv)                                              \
    do {                                                                      \
        sqv += A.x*A.x + A.y*A.y + A.z*A.z + A.w*A.w                          \
             + Bv.x*Bv.x + Bv.y*Bv.y + Bv.z*Bv.z + Bv.w*Bv.w;                 \
        short8 pk;                                                            \
        pk[0]=bfc(A.x); pk[1]=bfc(A.y); pk[2]=bfc(A.z); pk[3]=bfc(A.w);       \
        pk[4]=bfc(Bv.x); pk[5]=bfc(Bv.y); pk[6]=bfc(Bv.z); pk[7]=bfc(Bv.w);   \
        *(short8*)(smem + (nb) + dst + (off)) = pk;                           \
    } while (0)
#define WRSET(P, nb)                                                          \
    do { WRQ(sq0, nb, 0, P##0, P##1);      WRQ(sq1, nb, 4096, P##2, P##3);    \
         WRQ(sq2, nb, 8192, P##4, P##5);   WRQ(sq3, nb, 12288, P##6, P##7);   \
         WRQ(sq4, nb, 16384, P##8, P##9);  WRQ(sq5, nb, 20480, P##10, P##11); } while (0)

    // read addressing: row pitch 64B; phys slot = lg ^ ((l15>>1)&3)
    int qr = w & 3;                               // p-quarter within 256
    int Aoff = (w < 4) ? 0 : 8192;
    int Boff = (w < 4) ? 16384 : 20480;
    int slot = (lg ^ ((l15 >> 1) & 3)) * 16;
    int Abase = Aoff + (qr * 64 + l15) * 64 + slot;   // +i*1024
    int Bbase = Boff + l15 * 64 + slot;               // +j*1024

    f32x4 z = {0.f, 0.f, 0.f, 0.f};
    f32x4 a00=z,a01=z,a02=z,a03=z,a04=z,a05=z,a06=z,a07=z;
    f32x4 a10=z,a11=z,a12=z,a13=z,a14=z,a15=z,a16=z,a17=z;
    f32x4 a20=z,a21=z,a22=z,a23=z,a24=z,a25=z,a26=z,a27=z;
    f32x4 a30=z,a31=z,a32=z,a33=z,a34=z,a35=z,a36=z,a37=z;

#define MM(i, j, fa, fb) a##i##j = __builtin_amdgcn_mfma_f32_16x16x32_bf16(fa, fb, a##i##j, 0, 0, 0)
#define COMPUTE(cb)                                                           \
    do {                                                                      \
        const char* bp = smem + (cb);                                         \
        short8 fa0 = *(const short8*)(bp + Abase + 0);                        \
        short8 fa1 = *(const short8*)(bp + Abase + 1024);                     \
        short8 fa2 = *(const short8*)(bp + Abase + 2048);                     \
        short8 fa3 = *(const short8*)(bp + Abase + 3072);                     \
        short8 g0 = *(const short8*)(bp + Bbase + 0);                         \
        short8 g1 = *(const short8*)(bp + Bbase + 1024);                      \
        short8 g2 = *(const short8*)(bp + Bbase + 2048);                      \
        short8 g3 = *(const short8*)(bp + Bbase + 3072);                      \
        __builtin_amdgcn_s_setprio(1);                                        \
        MM(0,0,fa0,g0); MM(1,0,fa1,g0); MM(2,0,fa2,g0); MM(3,0,fa3,g0);       \
        MM(0,1,fa0,g1); MM(1,1,fa1,g1); MM(2,1,fa2,g1); MM(3,1,fa3,g1);       \
        MM(0,2,fa0,g2); MM(1,2,fa1,g2); MM(2,2,fa2,g2); MM(3,2,fa3,g2);       \
        MM(0,3,fa0,g3); MM(1,3,fa1,g3); MM(2,3,fa2,g3); MM(3,3,fa3,g3);       \
        __builtin_amdgcn_s_setprio(0);                                        \
        g0 = *(const short8*)(bp + Bbase + 4096);                             \
        g1 = *(const short8*)(bp + Bbase + 5120);                             \
        g2 = *(const short8*)(bp + Bbase + 6144);                             \
        g3 = *(const short8*)(bp + Bbase + 7168);                             \
        __builtin_amdgcn_s_setprio(1);                                        \
        MM(0,4,fa0,g0); MM(1,4,fa1,g0); MM(2,4,fa2,g0); MM(3,4,fa3,g0);       \
        MM(0,5,fa0,g1); MM(1,5,fa1,g1); MM(2,5,fa2,g1); MM(3,5,fa3,g1);       \
        MM(0,6,fa0,g2); MM(1,6,fa1,g2); MM(2,6,fa2,g2); MM(3,6,fa3,g2);       \
        MM(0,7,fa0,g3); MM(1,7,fa1,g3); MM(2,7,fa2,g3); MM(3,7,fa3,g3);       \
        __builtin_amdgcn_s_setprio(0);                                        \
    } while (0)

    // prologue: tile0 via E (one stall, once); tiles 1,2 in flight in O,E
    LDSET(E, 0);
    WRSET(E, 0);
    LDSET(O, (size_t)BK);
    LDSET(E, (size_t)(2 * BK));
    __syncthreads();

    // iter t: buf t%2 holds tile t; set[(t+1)%2] holds tile t+1 (rested 2 iters)
#pragma unroll 2
    for (int t = 0; t < 24; ++t) {
        int cb = (t & 1) * 49152;
        int nb = cb ^ 49152;
        COMPUTE(cb);
        if (t & 1) {                       // t odd: t+1 even -> set E
            if (t < 23) WRSET(E, nb);
            if (t < 21) LDSET(E, (size_t)(t + 3) * BK);
        } else {                           // t even: t+1 odd -> set O
            if (t < 23) WRSET(O, nb);
            if (t < 21) LDSET(O, (size_t)(t + 3) * BK);
        }
        __syncthreads();
    }
#undef COMPUTE
#undef MM
#undef WRSET
#undef WRQ
#undef LDSET

    // finalize norms: quad-reduce (lanes ln=0..3 share a row-segment)
    sq0 += __shfl_xor(sq0, 1); sq0 += __shfl_xor(sq0, 2);
    sq1 += __shfl_xor(sq1, 1); sq1 += __shfl_xor(sq1, 2);
    sq2 += __shfl_xor(sq2, 1); sq2 += __shfl_xor(sq2, 2);
    sq3 += __shfl_xor(sq3, 1); sq3 += __shfl_xor(sq3, 2);
    sq4 += __shfl_xor(sq4, 1); sq4 += __shfl_xor(sq4, 2);
    sq5 += __shfl_xor(sq5, 1); sq5 += __shfl_xor(sq5, 2);
    if (ln == 0) {
        norms[srow] = sq0;                 // Ah rows 0-127
        norms[128 + srow] = sq1;           // Ah rows 128-255
        norms[256 + srow] = sq2;           // At rows 0-127
        norms[384 + srow] = sq3;           // At rows 128-255
        norms[512 + srow] = sq4;           // Bh rows 0-127
        norms[640 + srow] = sq5;           // Bt rows 0-127
    }
    __syncthreads();

    // scale raw dots -> cosines: a[i][j][r] *= rsqrt(nA[p]) * rsqrt(nB[t])
    {
        const float* nA = norms + ((w < 4) ? 0 : 256);
        const float* nB = norms + ((w < 4) ? 512 : 640);
        float ivB0 = rsqrtf(nB[0 * 16 + l15]), ivB1 = rsqrtf(nB[1 * 16 + l15]);
        float ivB2 = rsqrtf(nB[2 * 16 + l15]), ivB3 = rsqrtf(nB[3 * 16 + l15]);
        float ivB4 = rsqrtf(nB[4 * 16 + l15]), ivB5 = rsqrtf(nB[5 * 16 + l15]);
        float ivB6 = rsqrtf(nB[6 * 16 + l15]), ivB7 = rsqrtf(nB[7 * 16 + l15]);
#define SCJ(ii, jj) { a##ii##jj[0] *= s0 * ivB##jj; a##ii##jj[1] *= s1 * ivB##jj; \
                      a##ii##jj[2] *= s2 * ivB##jj; a##ii##jj[3] *= s3 * ivB##jj; }
#define SCA(ii) { float s0 = rsqrtf(nA[qr * 64 + ii * 16 + lg * 4 + 0]);      \
                  float s1 = rsqrtf(nA[qr * 64 + ii * 16 + lg * 4 + 1]);      \
                  float s2 = rsqrtf(nA[qr * 64 + ii * 16 + lg * 4 + 2]);      \
                  float s3 = rsqrtf(nA[qr * 64 + ii * 16 + lg * 4 + 3]);      \
                  SCJ(ii,0) SCJ(ii,1) SCJ(ii,2) SCJ(ii,3)                     \
                  SCJ(ii,4) SCJ(ii,5) SCJ(ii,6) SCJ(ii,7) }
        SCA(0) SCA(1) SCA(2) SCA(3)
#undef SCA
#undef SCJ
    }
    __syncthreads();

    // epilogue (R8-verified shape): H-wave wp + T-wave wp via swizzled LDS.
    float* bwv = (float*)(smem + 40960);          // [256]
    int*   bwt = (int*)(smem + 43008);            // [256]
    int wp = w & 3;
    char* xrow = smem + (wp * 64 + l) * 128;      // 32KB exchange region
    int qsw = l & 7;

#define XW(q, v) *(f32x4*)(xrow + (((q) ^ qsw) * 16)) = (v)
#define XR(q)    *(const f32x4*)(xrow + (((q) ^ qsw) * 16))

#define ASTEP(ii, jj, rr, TQ)                                                 \
        { float h = a##ii##jj[rr]; float tv = (TQ)[rr];                       \
          bool ok = (h > THRESH) && (tv > THRESH);                            \
          float sc = ok ? 0.5f * (h + tv) : -INFINITY;                        \
          if (sc > bv) { bv = sc; bt = jj * 16 + l15; } }

#define AMX(ii, rr)                                                           \
    {   float bv = -INFINITY; int bt = 0x7fffffff;                            \
        ASTEP(ii, 0, rr, t0) ASTEP(ii, 1, rr, t1)                             \
        ASTEP(ii, 2, rr, t2) ASTEP(ii, 3, rr, t3)                             \
        ASTEP(ii, 4, rr, t4) ASTEP(ii, 5, rr, t5)                             \
        ASTEP(ii, 6, rr, t6) ASTEP(ii, 7, rr, t7)                             \
        for (int m = 1; m < 16; m <<= 1) {                                    \
            float v2 = __shfl_xor(bv, m); int q2 = __shfl_xor(bt, m);         \
            if (v2 > bv || (v2 == bv && q2 < bt)) { bv = v2; bt = q2; }       \
        }                                                                     \
        if (l15 == 0) { int p = qr * 64 + ii * 16 + lg * 4 + rr;              \
            bwv[p] = bv; bwt[p] = bt; }                                       \
    }

#define EPI(ii)                                                               \
    if (w >= 4) { XW(0, a##ii##0); XW(1, a##ii##1); XW(2, a##ii##2);          \
                  XW(3, a##ii##3); XW(4, a##ii##4); XW(5, a##ii##5);          \
                  XW(6, a##ii##6); XW(7, a##ii##7); }                         \
    __syncthreads();                                                          \
    if (w < 4) {                                                              \
        f32x4 t0 = XR(0), t1 = XR(1), t2 = XR(2), t3 = XR(3);                 \
        f32x4 t4 = XR(4), t5 = XR(5), t6 = XR(6), t7 = XR(7);                 \
        AMX(ii, 0) AMX(ii, 1) AMX(ii, 2) AMX(ii, 3)                           \
    }                                                                         \
    __syncthreads();

    EPI(0)
    EPI(1)
    EPI(2)
    EPI(3)
#undef EPI
#undef AMX
#undef ASTEP
#undef XW
#undef XR

    if (tid < 256) {
        float v = bwv[tid]; int t1 = bwt[tid];
        int grow = b * PP + pblk * 256 + tid;
        cand_v[(size_t)grow * 4 + tblk] = v;
        cand_t[(size_t)grow * 4 + tblk] = (v > -INFINITY) ? (tblk * 128 + t1) : 0x7fffffff;
    }
}

// ---------------- stage 3: fused merge + per-row NLL -------------------------
__global__ void nll_kernel(const float* __restrict__ preds,
                           const float* __restrict__ cand_v,
                           const int* __restrict__ cand_t,
                           const float* __restrict__ trip,
                           float* __restrict__ partials) {
    int w = threadIdx.x >> 6, l = threadIdx.x & 63;
    int row = blockIdx.x * 4 + w;
    const float* x = preds + (size_t)row * CC;

    float v = (l < 4) ? cand_v[(size_t)row * 4 + l] : -INFINITY;
    int  tt = (l < 4) ? cand_t[(size_t)row * 4 + l] : 0x7fffffff;
#pragma unroll
    for (int m = 1; m < 4; m <<= 1) {
        float v2 = __shfl_xor(v, m); int t2 = __shfl_xor(tt, m);
        if (v2 > v || (v2 == v && t2 < tt)) { v = v2; tt = t2; }
    }
    int bb = row >> 9;
    int tg = 0;
    if (l == 0 && v > -INFINITY)
        tg = (int)trip[((size_t)bb * TT + tt) * (2 * DD + 1) + DD];
    tg = __shfl(tg, 0);

    float a = x[l];
    float b2 = (l + 64 < CC) ? x[l + 64] : -INFINITY;
    float mx = fmaxf(a, b2);
    for (int m = 32; m; m >>= 1) mx = fmaxf(mx, __shfl_xor(mx, m));
    float e = __expf(a - mx) + ((l + 64 < CC) ? __expf(b2 - mx) : 0.0f);
    for (int m = 32; m; m >>= 1) e += __shfl_xor(e, m);

    __shared__ float part[4];
    if (l == 0) part[w] = mx + logf(e) - x[tg];
    __syncthreads();
    if (threadIdx.x == 0)
        partials[blockIdx.x] = part[0] + part[1] + part[2] + part[3];
}

// ---------------- stage 4: final mean ----------------------------------------
__global__ void final_reduce_kernel(const float* __restrict__ partials, int n,
                                    float* __restrict__ out) {
    float s = 0.f;
    for (int i = threadIdx.x; i < n; i += 256) s += partials[i];
    for (int m = 32; m; m >>= 1) s += __shfl_xor(s, m);
    __shared__ float ps[4];
    if ((threadIdx.x & 63) == 0) ps[threadIdx.x >> 6] = s;
    __syncthreads();
    if (threadIdx.x == 0)
        out[0] = (ps[0] + ps[1] + ps[2] + ps[3]) / (float)(BB * PP);
}

extern "C" void kernel_launch(void* const* d_in, const int* in_sizes, int n_in,
                              void* d_out, int out_size, void* d_ws, size_t ws_size,
                              hipStream_t stream) {
    const float* pairs = (const float*)d_in[0];  // [B,P,1536]
    const float* preds = (const float*)d_in[1];  // [B,P,97]
    const float* trip  = (const float*)d_in[2];  // [B,T,1537]
    float* out = (float*)d_out;

    char* p = (char*)d_ws;
    float* cand_v = (float*)p;       p += (size_t)BB * PP * 4 * sizeof(float);  // 256KB
    int* cand_t = (int*)p;           p += (size_t)BB * PP * 4 * sizeof(int);    // 256KB
    float* partials = (float*)p;                                                // 16KB

    match_kernel<<<BB * 8, 512, 0, stream>>>(pairs, trip, cand_v, cand_t);
    nll_kernel<<<BB * PP / 4, 256, 0, stream>>>(preds, cand_v, cand_t, trip, partials);
    final_reduce_kernel<<<1, 256, 0, stream>>>(partials, BB * PP / 4, out);
}

// Round 18
// 73.777 us; speedup vs baseline: 2.4639x; 2.4639x over previous
//
#include <hip/hip_runtime.h>
#include <hip/hip_bf16.h>
#include <math.h>

#define DD 768
#define BB 32
#define PP 512
#define TT 512
#define CC 97
#define THRESH 0.8f
#define BK 32

typedef __attribute__((ext_vector_type(8))) short short8;
typedef __attribute__((ext_vector_type(4))) float f32x4;
typedef float4 f4u __attribute__((aligned(4)));

__device__ __forceinline__ short bfc(float x) {
    __hip_bfloat16 h = __float2bfloat16(x);
    return *(short*)&h;
}

// ---------------- fused match: raw fp32 -> bf16 staged dual-GEMM -------------
// R18 == R10 verbatim (best measured: 73.4us total). Cosine trick: stage RAW
// values (fp32->bf16 in registers during staging), MFMA computes raw dots;
// per-row sum-of-squares accumulated from the SAME fp32 staging registers
// (norms exact-fp32, dots bf16: error ~0.4% vs 0.2 absolute discrete
// margins). Epilogue scales by rsqrt(nA)*rsqrt(nB) then thresholds.
// Geometry: 256 blocks, 512 thr = 8 waves, tile 256p x 128t, BK=32, 24 steps.
// Waves 0-3 H, 4-7 T; wave owns 64p x 128t (4x8 frags). 2 x 48KB LDS buffers,
// 1-deep reg prefetch (loads issued before COMPUTE, written after), ONE
// barrier per step. Slot swizzle verified (chunk c at slot c^((ro>>1)&3)).
// Post-R17 note: do NOT deepen staging on this tile (spills: 274MB scratch)
// and do NOT cap launch_bounds tighter (R11: 358MB spill).
__global__ __launch_bounds__(512, 2) void match_kernel(
        const float* __restrict__ pairs, const float* __restrict__ trip,
        float* __restrict__ cand_v, int* __restrict__ cand_t) {
    __shared__ __align__(16) char smem[98304];    // 2 x 48KB (Ah16|At16|Bh8|Bt8)
    __shared__ float norms[768];                  // [Ah256|At256|Bh128|Bt128]

    // XCD swizzle (256 blocks, %8==0 -> bijective); batch b lives on XCD b/4
    int bid = blockIdx.x;
    int swz = (bid & 7) * 32 + (bid >> 3);
    int b = swz >> 3, sub = swz & 7;
    int pblk = sub >> 2, tblk = sub & 3;          // 2 p-blocks x 4 t-blocks

    int tid = threadIdx.x;
    int w = tid >> 6, l = tid & 63;
    int l15 = l & 15, lg = l >> 4;
    int ln = tid & 3;

    const float* pairs_b = pairs + ((size_t)b * PP + pblk * 256) * (2 * DD);
    const float* trip_b  = trip  + ((size_t)b * TT + tblk * 128) * (2 * DD + 1);

    // 6 staging pieces per thread: piece r covers seg=(tid+512r)>>2 of 768
    // 64B-row-segments [Ah rows 0..255 | At 0..255 | Bh 0..127 | Bt 0..127],
    // 16B lane ln; source chunk = ln ^ ((local_row>>1)&3) (swizzle, src side).
    int s0r = tid >> 2;                   int x0 = ln ^ ((s0r >> 1) & 3);
    int s1r = ((tid + 512) >> 2);         int x1 = ln ^ ((s1r >> 1) & 3);
    int s2r = ((tid + 1024) >> 2) - 256;  int x2 = ln ^ ((s2r >> 1) & 3);
    int s3r = ((tid + 1536) >> 2) - 256;  int x3 = ln ^ ((s3r >> 1) & 3);
    int s4r = ((tid + 2048) >> 2) - 512;  int x4 = ln ^ ((s4r >> 1) & 3);
    int s5r = ((tid + 2560) >> 2) - 640;  int x5 = ln ^ ((s5r >> 1) & 3);
    const float* sp0 = pairs_b + (size_t)s0r * 1536 + x0 * 8;
    const float* sp1 = pairs_b + (size_t)s1r * 1536 + x1 * 8;
    const float* sp2 = pairs_b + (size_t)s2r * 1536 + 768 + x2 * 8;
    const float* sp3 = pairs_b + (size_t)s3r * 1536 + 768 + x3 * 8;
    const float* sp4 = trip_b + (size_t)s4r * 1537 + x4 * 8;
    const float* sp5 = trip_b + (size_t)s5r * 1537 + 769 + x5 * 8;
    int dst0 = tid * 16;
    int dst1 = 8192 + tid * 16;
    int dst2 = 16384 + tid * 16;
    int dst3 = 24576 + tid * 16;
    int dst4 = 32768 + tid * 16;
    int dst5 = 40960 + tid * 16;

    float4 va0, va1, va2, va3, va4, va5, vb0, vb1, vb2, vb3, vb4, vb5;
    float sq0 = 0.f, sq1 = 0.f, sq2 = 0.f, sq3 = 0.f, sq4 = 0.f, sq5 = 0.f;

#define LD(r, ko)                                                             \
    do { va##r = *(const f4u*)(sp##r + (ko));                                 \
         vb##r = *(const f4u*)(sp##r + (ko) + 4); } while (0)
#define WRP(r, nb)                                                            \
    do {                                                                      \
        sq##r += va##r.x*va##r.x + va##r.y*va##r.y + va##r.z*va##r.z          \
               + va##r.w*va##r.w + vb##r.x*vb##r.x + vb##r.y*vb##r.y          \
               + vb##r.z*vb##r.z + vb##r.w*vb##r.w;                           \
        short8 pk;                                                            \
        pk[0]=bfc(va##r.x); pk[1]=bfc(va##r.y); pk[2]=bfc(va##r.z);           \
        pk[3]=bfc(va##r.w); pk[4]=bfc(vb##r.x); pk[5]=bfc(vb##r.y);           \
        pk[6]=bfc(vb##r.z); pk[7]=bfc(vb##r.w);                               \
        *(short8*)(smem + (nb) + dst##r) = pk;                                \
    } while (0)

    // read addressing: row pitch 64B; phys slot = lg ^ ((l15>>1)&3)
    int qr = w & 3;
    int Aoff = (w < 4) ? 0 : 16384;
    int Boff = (w < 4) ? 32768 : 40960;
    int slot = (lg ^ ((l15 >> 1) & 3)) * 16;
    int Abase = Aoff + (qr * 64 + l15) * 64 + slot;   // +i*1024
    int Bbase = Boff + l15 * 64 + slot;               // +j*1024

    f32x4 z = {0.f, 0.f, 0.f, 0.f};
    f32x4 a00=z,a01=z,a02=z,a03=z,a04=z,a05=z,a06=z,a07=z;
    f32x4 a10=z,a11=z,a12=z,a13=z,a14=z,a15=z,a16=z,a17=z;
    f32x4 a20=z,a21=z,a22=z,a23=z,a24=z,a25=z,a26=z,a27=z;
    f32x4 a30=z,a31=z,a32=z,a33=z,a34=z,a35=z,a36=z,a37=z;

#define MM(i, j, fa, fb) a##i##j = __builtin_amdgcn_mfma_f32_16x16x32_bf16(fa, fb, a##i##j, 0, 0, 0)
#define COMPUTE(cb)                                                           \
    do {                                                                      \
        const char* bp = smem + (cb);                                         \
        short8 fa0 = *(const short8*)(bp + Abase + 0);                        \
        short8 fa1 = *(const short8*)(bp + Abase + 1024);                     \
        short8 fa2 = *(const short8*)(bp + Abase + 2048);                     \
        short8 fa3 = *(const short8*)(bp + Abase + 3072);                     \
        short8 g0 = *(const short8*)(bp + Bbase + 0);                         \
        short8 g1 = *(const short8*)(bp + Bbase + 1024);                      \
        short8 g2 = *(const short8*)(bp + Bbase + 2048);                      \
        short8 g3 = *(const short8*)(bp + Bbase + 3072);                      \
        __builtin_amdgcn_s_setprio(1);                                        \
        MM(0,0,fa0,g0); MM(1,0,fa1,g0); MM(2,0,fa2,g0); MM(3,0,fa3,g0);       \
        MM(0,1,fa0,g1); MM(1,1,fa1,g1); MM(2,1,fa2,g1); MM(3,1,fa3,g1);       \
        MM(0,2,fa0,g2); MM(1,2,fa1,g2); MM(2,2,fa2,g2); MM(3,2,fa3,g2);       \
        MM(0,3,fa0,g3); MM(1,3,fa1,g3); MM(2,3,fa2,g3); MM(3,3,fa3,g3);       \
        __builtin_amdgcn_s_setprio(0);                                        \
        g0 = *(const short8*)(bp + Bbase + 4096);                             \
        g1 = *(const short8*)(bp + Bbase + 5120);                             \
        g2 = *(const short8*)(bp + Bbase + 6144);                             \
        g3 = *(const short8*)(bp + Bbase + 7168);                             \
        __builtin_amdgcn_s_setprio(1);                                        \
        MM(0,4,fa0,g0); MM(1,4,fa1,g0); MM(2,4,fa2,g0); MM(3,4,fa3,g0);       \
        MM(0,5,fa0,g1); MM(1,5,fa1,g1); MM(2,5,fa2,g1); MM(3,5,fa3,g1);       \
        MM(0,6,fa0,g2); MM(1,6,fa1,g2); MM(2,6,fa2,g2); MM(3,6,fa3,g2);       \
        MM(0,7,fa0,g3); MM(1,7,fa1,g3); MM(2,7,fa2,g3); MM(3,7,fa3,g3);       \
        __builtin_amdgcn_s_setprio(0);                                        \
    } while (0)

    // prologue: tile 0 -> buf0
    LD(0, 0); LD(1, 0); LD(2, 0); LD(3, 0); LD(4, 0); LD(5, 0);
    WRP(0, 0); WRP(1, 0); WRP(2, 0); WRP(3, 0); WRP(4, 0); WRP(5, 0);
    __syncthreads();

#pragma unroll 2
    for (int t = 0; t < 24; ++t) {
        int cb = (t & 1) * 49152;
        int nb = cb ^ 49152;
        if (t < 23) {                     // issue next tile's loads (T14 early)
            size_t ko = (size_t)(t + 1) * BK;
            LD(0, ko); LD(1, ko); LD(2, ko); LD(3, ko); LD(4, ko); LD(5, ko);
        }
        COMPUTE(cb);                      // MFMA on current tile hides HBM
        if (t < 23) {                     // write-late: sq accum + cvt + ds_write
            WRP(0, nb); WRP(1, nb); WRP(2, nb);
            WRP(3, nb); WRP(4, nb); WRP(5, nb);
        }
        __syncthreads();
    }
#undef COMPUTE
#undef MM
#undef WRP
#undef LD

    // finalize norms: quad-reduce (lanes ln=0..3 share a row-segment)
    sq0 += __shfl_xor(sq0, 1); sq0 += __shfl_xor(sq0, 2);
    sq1 += __shfl_xor(sq1, 1); sq1 += __shfl_xor(sq1, 2);
    sq2 += __shfl_xor(sq2, 1); sq2 += __shfl_xor(sq2, 2);
    sq3 += __shfl_xor(sq3, 1); sq3 += __shfl_xor(sq3, 2);
    sq4 += __shfl_xor(sq4, 1); sq4 += __shfl_xor(sq4, 2);
    sq5 += __shfl_xor(sq5, 1); sq5 += __shfl_xor(sq5, 2);
    if (ln == 0) {
        norms[tid >> 2] = sq0;
        norms[(tid + 512) >> 2] = sq1;
        norms[(tid + 1024) >> 2] = sq2;
        norms[(tid + 1536) >> 2] = sq3;
        norms[(tid + 2048) >> 2] = sq4;
        norms[(tid + 2560) >> 2] = sq5;
    }
    __syncthreads();

    // scale raw dots -> cosines: a[i][j][r] *= rsqrt(nA[p]) * rsqrt(nB[t])
    {
        const float* nA = norms + ((w < 4) ? 0 : 256);
        const float* nB = norms + ((w < 4) ? 512 : 640);
        float ivB0 = rsqrtf(nB[0 * 16 + l15]), ivB1 = rsqrtf(nB[1 * 16 + l15]);
        float ivB2 = rsqrtf(nB[2 * 16 + l15]), ivB3 = rsqrtf(nB[3 * 16 + l15]);
        float ivB4 = rsqrtf(nB[4 * 16 + l15]), ivB5 = rsqrtf(nB[5 * 16 + l15]);
        float ivB6 = rsqrtf(nB[6 * 16 + l15]), ivB7 = rsqrtf(nB[7 * 16 + l15]);
#define SCJ(ii, jj) { a##ii##jj[0] *= s0 * ivB##jj; a##ii##jj[1] *= s1 * ivB##jj; \
                      a##ii##jj[2] *= s2 * ivB##jj; a##ii##jj[3] *= s3 * ivB##jj; }
#define SCA(ii) { float s0 = rsqrtf(nA[qr * 64 + ii * 16 + lg * 4 + 0]);      \
                  float s1 = rsqrtf(nA[qr * 64 + ii * 16 + lg * 4 + 1]);      \
                  float s2 = rsqrtf(nA[qr * 64 + ii * 16 + lg * 4 + 2]);      \
                  float s3 = rsqrtf(nA[qr * 64 + ii * 16 + lg * 4 + 3]);      \
                  SCJ(ii,0) SCJ(ii,1) SCJ(ii,2) SCJ(ii,3)                     \
                  SCJ(ii,4) SCJ(ii,5) SCJ(ii,6) SCJ(ii,7) }
        SCA(0) SCA(1) SCA(2) SCA(3)
#undef SCA
#undef SCJ
    }
    __syncthreads();

    // epilogue: H-wave wp combines with T-wave wp via swizzled LDS exchange.
    float* bwv = (float*)(smem + 32768);          // [256]
    int*   bwt = (int*)(smem + 33792);            // [256]
    int wp = w & 3;
    char* xrow = smem + (wp * 64 + l) * 128;      // 32KB exchange region
    int qsw = l & 7;

#define XW(q, v) *(f32x4*)(xrow + (((q) ^ qsw) * 16)) = (v)
#define XR(q)    *(const f32x4*)(xrow + (((q) ^ qsw) * 16))

#define ASTEP(ii, jj, rr, TQ)                                                 \
        { float h = a##ii##jj[rr]; float tv = (TQ)[rr];                       \
          bool ok = (h > THRESH) && (tv > THRESH);                            \
          float sc = ok ? 0.5f * (h + tv) : -INFINITY;                        \
          if (sc > bv) { bv = sc; bt = jj * 16 + l15; } }

#define AMX(ii, rr)                                                           \
    {   float bv = -INFINITY; int bt = 0x7fffffff;                            \
        ASTEP(ii, 0, rr, t0) ASTEP(ii, 1, rr, t1)                             \
        ASTEP(ii, 2, rr, t2) ASTEP(ii, 3, rr, t3)                             \
        ASTEP(ii, 4, rr, t4) ASTEP(ii, 5, rr, t5)                             \
        ASTEP(ii, 6, rr, t6) ASTEP(ii, 7, rr, t7)                             \
        for (int m = 1; m < 16; m <<= 1) {                                    \
            float v2 = __shfl_xor(bv, m); int q2 = __shfl_xor(bt, m);         \
            if (v2 > bv || (v2 == bv && q2 < bt)) { bv = v2; bt = q2; }       \
        }                                                                     \
        if (l15 == 0) { int p = qr * 64 + ii * 16 + lg * 4 + rr;              \
            bwv[p] = bv; bwt[p] = bt; }                                       \
    }

#define EPI(ii)                                                               \
    if (w >= 4) { XW(0, a##ii##0); XW(1, a##ii##1); XW(2, a##ii##2);          \
                  XW(3, a##ii##3); XW(4, a##ii##4); XW(5, a##ii##5);          \
                  XW(6, a##ii##6); XW(7, a##ii##7); }                         \
    __syncthreads();                                                          \
    if (w < 4) {                                                              \
        f32x4 t0 = XR(0), t1 = XR(1), t2 = XR(2), t3 = XR(3);                 \
        f32x4 t4 = XR(4), t5 = XR(5), t6 = XR(6), t7 = XR(7);                 \
        AMX(ii, 0) AMX(ii, 1) AMX(ii, 2) AMX(ii, 3)                           \
    }                                                                         \
    __syncthreads();

    EPI(0)
    EPI(1)
    EPI(2)
    EPI(3)
#undef EPI
#undef AMX
#undef ASTEP
#undef XW
#undef XR

    if (tid < 256) {
        float v = bwv[tid]; int t1 = bwt[tid];
        int grow = b * PP + pblk * 256 + tid;
        cand_v[(size_t)grow * 4 + tblk] = v;
        cand_t[(size_t)grow * 4 + tblk] = (v > -INFINITY) ? (tblk * 128 + t1) : 0x7fffffff;
    }
}

// ---------------- stage 3: fused merge + per-row NLL -------------------------
// block = 256 = 4 waves, one row per wave. Lanes 0-3 merge the 4 t-block
// candidates; rel id read directly from trip column D; wave log-softmax C=97.
__global__ void nll_kernel(const float* __restrict__ preds,
                           const float* __restrict__ cand_v,
                           const int* __restrict__ cand_t,
                           const float* __restrict__ trip,
                           float* __restrict__ partials) {
    int w = threadIdx.x >> 6, l = threadIdx.x & 63;
    int row = blockIdx.x * 4 + w;
    const float* x = preds + (size_t)row * CC;

    float v = (l < 4) ? cand_v[(size_t)row * 4 + l] : -INFINITY;
    int  tt = (l < 4) ? cand_t[(size_t)row * 4 + l] : 0x7fffffff;
#pragma unroll
    for (int m = 1; m < 4; m <<= 1) {
        float v2 = __shfl_xor(v, m); int t2 = __shfl_xor(tt, m);
        if (v2 > v || (v2 == v && t2 < tt)) { v = v2; tt = t2; }
    }
    int bb = row >> 9;
    int tg = 0;
    if (l == 0 && v > -INFINITY)
        tg = (int)trip[((size_t)bb * TT + tt) * (2 * DD + 1) + DD];
    tg = __shfl(tg, 0);

    float a = x[l];
    float b2 = (l + 64 < CC) ? x[l + 64] : -INFINITY;
    float mx = fmaxf(a, b2);
    for (int m = 32; m; m >>= 1) mx = fmaxf(mx, __shfl_xor(mx, m));
    float e = __expf(a - mx) + ((l + 64 < CC) ? __expf(b2 - mx) : 0.0f);
    for (int m = 32; m; m >>= 1) e += __shfl_xor(e, m);

    __shared__ float part[4];
    if (l == 0) part[w] = mx + logf(e) - x[tg];
    __syncthreads();
    if (threadIdx.x == 0)
        partials[blockIdx.x] = part[0] + part[1] + part[2] + part[3];
}

// ---------------- stage 4: final mean ----------------------------------------
__global__ void final_reduce_kernel(const float* __restrict__ partials, int n,
                                    float* __restrict__ out) {
    float s = 0.f;
    for (int i = threadIdx.x; i < n; i += 256) s += partials[i];
    for (int m = 32; m; m >>= 1) s += __shfl_xor(s, m);
    __shared__ float ps[4];
    if ((threadIdx.x & 63) == 0) ps[threadIdx.x >> 6] = s;
    __syncthreads();
    if (threadIdx.x == 0)
        out[0] = (ps[0] + ps[1] + ps[2] + ps[3]) / (float)(BB * PP);
}

extern "C" void kernel_launch(void* const* d_in, const int* in_sizes, int n_in,
                              void* d_out, int out_size, void* d_ws, size_t ws_size,
                              hipStream_t stream) {
    const float* pairs = (const float*)d_in[0];  // [B,P,1536]
    const float* preds = (const float*)d_in[1];  // [B,P,97]
    const float* trip  = (const float*)d_in[2];  // [B,T,1537]
    float* out = (float*)d_out;

    char* p = (char*)d_ws;
    float* cand_v = (float*)p;       p += (size_t)BB * PP * 4 * sizeof(float);  // 256KB
    int* cand_t = (int*)p;           p += (size_t)BB * PP * 4 * sizeof(int);    // 256KB
    float* partials = (float*)p;                                                // 16KB

    match_kernel<<<BB * 8, 512, 0, stream>>>(pairs, trip, cand_v, cand_t);
    nll_kernel<<<BB * PP / 4, 256, 0, stream>>>(preds, cand_v, cand_t, trip, partials);
    final_reduce_kernel<<<1, 256, 0, stream>>>(partials, BB * PP / 4, out);
}